// Round 3
// baseline (430.803 us; speedup 1.0000x reference)
//
#include <hip/hip_runtime.h>
#include <hip/hip_bf16.h>
#include <stdint.h>

typedef __attribute__((ext_vector_type(8))) __bf16 bf16x8;
typedef __attribute__((ext_vector_type(4))) float f32x4;

static __device__ __forceinline__ unsigned short f2bf(float f) {
    unsigned int u = __float_as_uint(f);
    unsigned int r = (u + 0x7fffu + ((u >> 16) & 1u)) >> 16;
    return (unsigned short)r;
}

// ---------------- Kernel 1: weight fp32 -> bf16 ----------------
__global__ __launch_bounds__(256) void wconv_kernel(
    const float* __restrict__ w, unsigned short* __restrict__ wb)
{
    const int i = blockIdx.x * 256 + threadIdx.x;
    const float4 v = ((const float4*)w)[i];
    ushort4 o;
    o.x = f2bf(v.x); o.y = f2bf(v.y); o.z = f2bf(v.z); o.w = f2bf(v.w);
    ((ushort4*)wb)[i] = o;
}

// ---------------- Kernel 2: fused prune + variance-scale + 256x256x64 GEMM ----------------
// C[m,n] = v[m] * (prune24(x)[m,:] @ W[n,:])   with v factored out to the epilogue.
// A staged from x fp32 by registers (prune inline, bf16 pack, swizzled ds_write);
// B staged via global_load_lds (linear dest, pre-swizzled source) as in round 2.
// Per-row variance partials accumulated during staging; v computed once at the end.
#define KD 1024
#define ND 1024

#define GLL16(gp, lp)                                                          \
    __builtin_amdgcn_global_load_lds(                                          \
        (const __attribute__((address_space(1))) void*)(gp),                   \
        (__attribute__((address_space(3))) void*)(lp), 16, 0, 0)

#define VMW(n) asm volatile("s_waitcnt vmcnt(" #n ")" ::: "memory")

#define BSTAGE(BUFB, kh, ktoff) {                                              \
    const unsigned short* _s = bG + (ktoff) + (kh) * 32;                       \
    char* _dp = smem + 65536 + (BUFB) + (kh) * 16384 + w * 1024;               \
    GLL16(_s, _dp); GLL16(_s + 128 * KD, _dp + 8192); }

#define LOADA(BUFB, mh, ks) {                                                  \
    const char* _ab = smem + (BUFB) + (ks) * 16384 + aR0 + (mh) * 4096;        \
    af[0] = *(const bf16x8*)(_ab);                                             \
    af[1] = *(const bf16x8*)(_ab + 1024);                                      \
    af[2] = *(const bf16x8*)(_ab + 2048);                                      \
    af[3] = *(const bf16x8*)(_ab + 3072); }

#define LOADB(BUFB, ks, bkA) {                                                 \
    const char* _bb = smem + 65536 + (BUFB) + (ks) * 16384 + bR0;              \
    bkA[0] = *(const bf16x8*)(_bb);                                            \
    bkA[1] = *(const bf16x8*)(_bb + 1024);                                     \
    bkA[2] = *(const bf16x8*)(_bb + 2048);                                     \
    bkA[3] = *(const bf16x8*)(_bb + 3072); }

#define AXLOAD(ktoff) {                                                        \
    ax0 = *(const float4*)(xT + (ktoff));                                      \
    ax1 = *(const float4*)(xT + (ktoff) + 4);                                  \
    ax2 = *(const float4*)(xT + (ktoff) + 8);                                  \
    ax3 = *(const float4*)(xT + (ktoff) + 12);                                 \
    ax4 = *(const float4*)(xT + (ktoff) + 32);                                 \
    ax5 = *(const float4*)(xT + (ktoff) + 36);                                 \
    ax6 = *(const float4*)(xT + (ktoff) + 40);                                 \
    ax7 = *(const float4*)(xT + (ktoff) + 44); }

#define PRUNE1(g, p) {                                                         \
    const float b0 = fabsf(g.x), b1 = fabsf(g.y), b2 = fabsf(g.z), b3 = fabsf(g.w); \
    const int r0 = (b1 >  b0) + (b2 >  b0) + (b3 >  b0);                       \
    const int r1 = (b0 >= b1) + (b2 >  b1) + (b3 >  b1);                       \
    const int r2 = (b0 >= b2) + (b1 >= b2) + (b3 >  b2);                       \
    const int r3 = (b0 >= b3) + (b1 >= b3) + (b2 >= b3);                       \
    p.x = (r0 < 2) ? g.x : 0.0f;                                               \
    p.y = (r1 < 2) ? g.y : 0.0f;                                               \
    p.z = (r2 < 2) ? g.z : 0.0f;                                               \
    p.w = (r3 < 2) ? g.w : 0.0f; }

#define PACK8(pa, pb, dstb) {                                                  \
    union { ushort h[8]; uint4 q; } _k;                                        \
    _k.h[0] = f2bf(pa.x); _k.h[1] = f2bf(pa.y);                                \
    _k.h[2] = f2bf(pa.z); _k.h[3] = f2bf(pa.w);                                \
    _k.h[4] = f2bf(pb.x); _k.h[5] = f2bf(pb.y);                                \
    _k.h[6] = f2bf(pb.z); _k.h[7] = f2bf(pb.w);                                \
    *(uint4*)(dstb) = _k.q; }

#define PRUNE_WRITE(DSTB, DOACC) {                                             \
    float4 p0, p1, p2, p3, p4, p5, p6, p7;                                     \
    PRUNE1(ax0, p0); PRUNE1(ax1, p1); PRUNE1(ax2, p2); PRUNE1(ax3, p3);        \
    PRUNE1(ax4, p4); PRUNE1(ax5, p5); PRUNE1(ax6, p6); PRUNE1(ax7, p7);        \
    if (DOACC) {                                                               \
        sx  += ((ax0.x+ax0.y)+(ax0.z+ax0.w)) + ((ax1.x+ax1.y)+(ax1.z+ax1.w))   \
             + ((ax2.x+ax2.y)+(ax2.z+ax2.w)) + ((ax3.x+ax3.y)+(ax3.z+ax3.w))   \
             + ((ax4.x+ax4.y)+(ax4.z+ax4.w)) + ((ax5.x+ax5.y)+(ax5.z+ax5.w))   \
             + ((ax6.x+ax6.y)+(ax6.z+ax6.w)) + ((ax7.x+ax7.y)+(ax7.z+ax7.w));  \
        sxx += (ax0.x*ax0.x + ax0.y*ax0.y + ax0.z*ax0.z + ax0.w*ax0.w)         \
             + (ax1.x*ax1.x + ax1.y*ax1.y + ax1.z*ax1.z + ax1.w*ax1.w)         \
             + (ax2.x*ax2.x + ax2.y*ax2.y + ax2.z*ax2.z + ax2.w*ax2.w)         \
             + (ax3.x*ax3.x + ax3.y*ax3.y + ax3.z*ax3.z + ax3.w*ax3.w)         \
             + (ax4.x*ax4.x + ax4.y*ax4.y + ax4.z*ax4.z + ax4.w*ax4.w)         \
             + (ax5.x*ax5.x + ax5.y*ax5.y + ax5.z*ax5.z + ax5.w*ax5.w)         \
             + (ax6.x*ax6.x + ax6.y*ax6.y + ax6.z*ax6.z + ax6.w*ax6.w)         \
             + (ax7.x*ax7.x + ax7.y*ax7.y + ax7.z*ax7.z + ax7.w*ax7.w);        \
        sp  += ((p0.x+p0.y)+(p0.z+p0.w)) + ((p1.x+p1.y)+(p1.z+p1.w))           \
             + ((p2.x+p2.y)+(p2.z+p2.w)) + ((p3.x+p3.y)+(p3.z+p3.w))           \
             + ((p4.x+p4.y)+(p4.z+p4.w)) + ((p5.x+p5.y)+(p5.z+p5.w))           \
             + ((p6.x+p6.y)+(p6.z+p6.w)) + ((p7.x+p7.y)+(p7.z+p7.w));          \
        spp += (p0.x*p0.x + p0.y*p0.y + p0.z*p0.z + p0.w*p0.w)                 \
             + (p1.x*p1.x + p1.y*p1.y + p1.z*p1.z + p1.w*p1.w)                 \
             + (p2.x*p2.x + p2.y*p2.y + p2.z*p2.z + p2.w*p2.w)                 \
             + (p3.x*p3.x + p3.y*p3.y + p3.z*p3.z + p3.w*p3.w)                 \
             + (p4.x*p4.x + p4.y*p4.y + p4.z*p4.z + p4.w*p4.w)                 \
             + (p5.x*p5.x + p5.y*p5.y + p5.z*p5.z + p5.w*p5.w)                 \
             + (p6.x*p6.x + p6.y*p6.y + p6.z*p6.z + p6.w*p6.w)                 \
             + (p7.x*p7.x + p7.y*p7.y + p7.z*p7.z + p7.w*p7.w);                \
    }                                                                          \
    PACK8(p0, p1, smem + (DSTB) + oA0);                                        \
    PACK8(p2, p3, smem + (DSTB) + oA1);                                        \
    PACK8(p4, p5, smem + (DSTB) + 16384 + oA0);                                \
    PACK8(p6, p7, smem + (DSTB) + 16384 + oA1); }

#define MFMA_BLOCK(mh, bkA)                                                    \
    __builtin_amdgcn_s_barrier();                                              \
    asm volatile("s_waitcnt lgkmcnt(0)" ::: "memory");                         \
    __builtin_amdgcn_s_setprio(1);                                             \
    _Pragma("unroll") for (int _i = 0; _i < 4; ++_i) {                         \
      _Pragma("unroll") for (int _n = 0; _n < 4; ++_n) {                       \
        acc[(mh)*4+_i][_n] = __builtin_amdgcn_mfma_f32_16x16x32_bf16(          \
            af[_i], bkA[_n], acc[(mh)*4+_i][_n], 0, 0, 0); } }                 \
    __builtin_amdgcn_s_setprio(0);                                             \
    __builtin_amdgcn_s_barrier();

__global__ __launch_bounds__(512, 2) void fused_gemm_kernel(
    const float* __restrict__ X,            // [32768][1024] fp32
    const unsigned short* __restrict__ Bw,  // [1024][1024] bf16 (W row-major)
    float* __restrict__ C)                  // [32768][1024] f32
{
    __shared__ char smem[131072];

    const int t = threadIdx.x;
    const int w = t >> 6, l = t & 63;
    const int wm = w >> 2, wn = w & 3;

    // XCD swizzle: each XCD gets contiguous m-range, n swept innermost -> x rows L2-hit
    const int bid = blockIdx.x;
    const int swz = (bid & 7) * 64 + (bid >> 3);
    const int tile_m = swz >> 2, tile_n = swz & 3;

    // ---- B staging params (GLL, proven in round 2) ----
    const int r0 = w * 16 + (l >> 2);
    const int gsrc = (l & 3) ^ ((l >> 3) & 3);
    const unsigned short* bG = Bw + (size_t)(tile_n * 256 + r0) * KD + gsrc * 8;

    // ---- A staging params (reg-staged from x fp32) ----
    const int arow = t >> 1;                   // row 0..255 within m-tile
    const float* xT = X + (size_t)(tile_m * 256 + arow) * KD + (t & 1) * 16;
    const int q0g = (t & 1) * 2;               // granule within 32-k half
    const int rx  = (t >> 2) & 3;              // (arow>>1)&3 row-XOR swizzle
    const int oA0 = arow * 64 + ((q0g       ^ rx) * 16);
    const int oA1 = arow * 64 + (((q0g | 1) ^ rx) * 16);

    // ---- reader bases ----
    const int gq  = (l >> 4) ^ ((l >> 1) & 3);
    const int aR0 = (wm * 128 + (l & 15)) * 64 + gq * 16;
    const int bR0 = (wn * 64 + (l & 15)) * 64 + gq * 16;

    f32x4 acc[8][4] = {};
    bf16x8 af[4], bk0[4], bk1[4];
    float4 ax0, ax1, ax2, ax3, ax4, ax5, ax6, ax7;
    float sx = 0.f, sxx = 0.f, sp = 0.f, spp = 0.f;

    // ---- prologue: tile 0 ----
    AXLOAD(0);                       // 8 A loads
    BSTAGE(0, 0, 0);                 // 2 GLL
    BSTAGE(0, 1, 0);                 // 2 GLL   (outstanding 12)
    VMW(4);                          // A loads done (leaves 4 B GLL)
    PRUNE_WRITE(0, 1);               // tile0 bf16 -> LDS buf0 (+ sums)
    VMW(2);                          // B kh0 done (leaves B kh1)
    __syncthreads();                 // seals ds_writes + all-wave GLL kh0

    // ---- main loop: invariant entering q0: 2 outstanding (B kh1 of this tile) ----
    for (int tt = 0; tt < 16; ++tt) {
        const int bufc = (tt & 1) << 15;
        const int bufn = bufc ^ 32768;
        const int ktoff = ((tt + 1) & 15) * 64;      // prefetch k-offset (wraps)
        const bool doacc = (tt != 15);               // skip wrapped tile-0 rerun

        // q0 (mh0,ks0)
        LOADA(bufc, 0, 0);
        LOADB(bufc, 0, bk0);
        AXLOAD(ktoff);                               // +8 -> 10 outstanding
        VMW(8);                                      // drain B kh1(tt) before barrier
        MFMA_BLOCK(0, bk0);

        // q1 (mh0,ks1)
        LOADA(bufc, 0, 1);
        LOADB(bufc, 1, bk1);
        BSTAGE(bufn, 0, ktoff);                      // +2 -> 10
        MFMA_BLOCK(0, bk1);

        // q2 (mh1,ks0)
        VMW(2);                                      // A prefetch loads in regs
        PRUNE_WRITE(bufn, doacc);
        LOADA(bufc, 1, 0);
        MFMA_BLOCK(1, bk0);

        // q3 (mh1,ks1)
        LOADA(bufc, 1, 1);
        BSTAGE(bufn, 1, ktoff);                      // +2 -> 4
        VMW(2);                                      // drain B kh0(tt+1) before barrier
        MFMA_BLOCK(1, bk1);
    }

    // ---- epilogue: per-row v, then scaled C write ----
    __syncthreads();
    float SX  = sx  + __shfl_xor(sx,  1);
    float SXX = sxx + __shfl_xor(sxx, 1);
    float SP  = sp  + __shfl_xor(sp,  1);
    float SPP = spp + __shfl_xor(spp, 1);
    float* vbuf = (float*)(smem + 32768);   // A buf1 region: clean after tt=15
    if ((t & 1) == 0) {
        const float var_x = (SXX - SX * SX * (1.0f / 1024.0f)) * (1.0f / 1023.0f);
        float var_p = (SPP - SP * SP * (1.0f / 1024.0f)) * (1.0f / 1023.0f);
        var_p = fmaxf(var_p, 1e-9f);
        vbuf[arow] = sqrtf(var_x / var_p);
    }
    __syncthreads();

    float* Cp = C + (size_t)(tile_m * 256 + wm * 128 + ((l >> 4) * 4)) * ND
                  + tile_n * 256 + wn * 64 + (l & 15);
    #pragma unroll
    for (int m = 0; m < 8; ++m) {
        const float4 vm = *(const float4*)&vbuf[wm * 128 + m * 16 + (l >> 4) * 4];
        #pragma unroll
        for (int n = 0; n < 4; ++n) {
            Cp[(size_t)(m * 16 + 0) * ND + n * 16] = acc[m][n][0] * vm.x;
            Cp[(size_t)(m * 16 + 1) * ND + n * 16] = acc[m][n][1] * vm.y;
            Cp[(size_t)(m * 16 + 2) * ND + n * 16] = acc[m][n][2] * vm.z;
            Cp[(size_t)(m * 16 + 3) * ND + n * 16] = acc[m][n][3] * vm.w;
        }
    }
}

extern "C" void kernel_launch(void* const* d_in, const int* in_sizes, int n_in,
                              void* d_out, int out_size, void* d_ws, size_t ws_size,
                              hipStream_t stream) {
    const float* x  = (const float*)d_in[0];   // [4,8192,1024] fp32
    const float* wt = (const float*)d_in[1];   // [1024,1024] fp32
    float* out = (float*)d_out;                // [4,8192,1024] fp32

    unsigned short* Wbf = (unsigned short*)d_ws;   // 2 MiB

    wconv_kernel<<<1024, 256, 0, stream>>>(wt, Wbf);
    fused_gemm_kernel<<<512, 512, 0, stream>>>(x, Wbf, out);
}